// Round 14
// baseline (143.279 us; speedup 1.0000x reference)
//
#include <hip/hip_runtime.h>

typedef _Float16 f16x8 __attribute__((ext_vector_type(8)));
typedef float f32x4 __attribute__((ext_vector_type(4)));

#define MDIM 64000
#define KD 512
#define NCOLS 514
#define BM 256
#define BN 64
#define KT 16      // K steps of 32
#define NT 8       // N tiles (cols 0..511); Nyquist analytic
#define NWG 2000   // 250 M-tiles x 8 N-tiles, %8==0

// global -> LDS direct DMA, 16B per lane, LDS dest = wave-uniform base + lane*16
#define GLOAD_LDS16(g, l)                                        \
  __builtin_amdgcn_global_load_lds(                              \
      (const __attribute__((address_space(1))) void*)(g),        \
      (__attribute__((address_space(3))) void*)(l), 16, 0, 0)

// Build interleaved f16 weight matrix Wb[n][k], n in [0,512):
//   n even -> real_kernel[n/2], n odd -> imag_kernel[n/2]
__global__ void prep_w(const float* __restrict__ rk, const float* __restrict__ ik,
                       _Float16* __restrict__ wb) {
  int n = blockIdx.x;
  int k = threadIdx.x;
  int bin = n >> 1;
  const float* src = (n & 1) ? ik : rk;
  wb[(size_t)n * KD + k] = (_Float16)src[bin * KD + k];
}

// Barrier-free main loop: B panel staged ONCE (64 KB), A direct-from-global.
// (512,3): VGPR cap ~170 >> natural ~100 -> no spill (r10 lesson);
// LDS 64 KB -> 2 blocks/CU, 16 waves/CU unsynchronized.
__global__ __launch_bounds__(512, 3)
void dft_gemm(const float* __restrict__ x, const _Float16* __restrict__ wb,
              float* __restrict__ out) {
  // Bp[row][k]: the block's full B panel, rows = 64 output cols, k = 512.
  // Chunk swizzle: logical 16B chunk c of row r at phys c^(r&7).
  __shared__ _Float16 Bp[BN * KD];  // 64 KB

  const int tid = threadIdx.x;
  const int l  = tid & 63;
  const int w  = tid >> 6;   // 8 waves
  const int lr = l & 15;
  const int lg = l >> 4;

  // T1: XCD swizzle (NWG%8==0). The 8 N-blocks of one M-slab -> same XCD L2.
  const int wgid = (blockIdx.x & 7) * (NWG / 8) + (blockIdx.x >> 3);
  const int mt = wgid >> 3, nt = wgid & 7;
  const int m0 = mt * BM, n0 = nt * BN;

  // ---- prologue: stage B panel once; one GLOAD = one row (64x16B = 1KB) ----
#pragma unroll
  for (int s = 0; s < 8; ++s) {
    int row = w * 8 + s;                 // wave-uniform
    int cl  = l ^ (row & 7);             // logical chunk for phys chunk l
    GLOAD_LDS16(wb + (size_t)(n0 + row) * KD + cl * 8, &Bp[row * KD]);
  }
  __syncthreads();  // the ONLY barrier: panel landed (vmcnt(0) drain)

  f32x4 acc[2][4] = {};                  // [fm][fn]
  float nyq[2] = {0.0f, 0.0f};
  const bool donyq = (nt == 0);

  // A direct: lane owns row m0 + w*32 + fm*16 + lr, k-slice lg*8..+7 per step
  const float* a0 = x + (size_t)(m0 + w * 32 + lr) * KD + lg * 8;

#pragma unroll
  for (int kt = 0; kt < KT; ++kt) {
    f16x8 av[2], bv[4];
#pragma unroll
    for (int fm = 0; fm < 2; ++fm) {
      f32x4 lo = *reinterpret_cast<const f32x4*>(a0 + (size_t)fm * 16 * KD + kt * 32);
      f32x4 hi = *reinterpret_cast<const f32x4*>(a0 + (size_t)fm * 16 * KD + kt * 32 + 4);
      f16x8 h;
      h[0] = (_Float16)lo[0]; h[1] = (_Float16)lo[1];
      h[2] = (_Float16)lo[2]; h[3] = (_Float16)lo[3];
      h[4] = (_Float16)hi[0]; h[5] = (_Float16)hi[1];
      h[6] = (_Float16)hi[2]; h[7] = (_Float16)hi[3];
      av[fm] = h;
      // Nyquist: k = kt*32+lg*8+j -> sign = (-1)^j; f32-exact
      if (donyq)
        nyq[fm] += (lo[0] - lo[1]) + (lo[2] - lo[3]) + (hi[0] - hi[1]) + (hi[2] - hi[3]);
    }
#pragma unroll
    for (int fn = 0; fn < 4; ++fn) {
      int row = fn * 16 + lr;
      int pc  = (kt * 4 + lg) ^ (row & 7);
      bv[fn] = *reinterpret_cast<const f16x8*>(&Bp[row * KD + pc * 8]);
    }
#pragma unroll
    for (int fm = 0; fm < 2; ++fm)
#pragma unroll
      for (int fn = 0; fn < 4; ++fn)
        acc[fm][fn] = __builtin_amdgcn_mfma_f32_16x16x32_f16(
            av[fm], bv[fn], acc[fm][fn], 0, 0, 0);
  }

  // ---- epilogue: C/D layout col=lane&15, row=(lane>>4)*4+reg ----
#pragma unroll
  for (int fm = 0; fm < 2; ++fm) {
#pragma unroll
    for (int rr = 0; rr < 4; ++rr) {
      int row = m0 + w * 32 + fm * 16 + lg * 4 + rr;
      size_t base = (size_t)row * NCOLS;
#pragma unroll
      for (int fn = 0; fn < 4; ++fn)
        out[base + n0 + fn * 16 + lr] = acc[fm][fn][rr];
    }
  }

  // ---- Nyquist: col 512 = sum_n (-1)^n x[n]; col 513 = 0 ----
  // lane covers k = lg's quarter; reduce over lg via xor 16/32.
  if (donyq) {
#pragma unroll
    for (int fm = 0; fm < 2; ++fm) {
      float t = nyq[fm];
      t += __shfl_xor(t, 16);
      t += __shfl_xor(t, 32);
      if (lg == 0) {
        size_t base = (size_t)(m0 + w * 32 + fm * 16 + lr) * NCOLS;
        out[base + 512] = t;
        out[base + 513] = 0.0f;
      }
    }
  }
}

extern "C" void kernel_launch(void* const* d_in, const int* in_sizes, int n_in,
                              void* d_out, int out_size, void* d_ws, size_t ws_size,
                              hipStream_t stream) {
  const float* x  = (const float*)d_in[0];
  const float* rk = (const float*)d_in[1];
  const float* ik = (const float*)d_in[2];
  float* out = (float*)d_out;
  _Float16* wb = (_Float16*)d_ws;  // 512*512*2 B = 512 KB scratch

  prep_w<<<dim3(KD), dim3(KD), 0, stream>>>(rk, ik, wb);

  dim3 grid(NWG);
  dft_gemm<<<grid, dim3(512), 0, stream>>>(x, wb, out);
}

// Round 15
// 141.511 us; speedup vs baseline: 1.0125x; 1.0125x over previous
//
#include <hip/hip_runtime.h>

typedef _Float16 f16x8 __attribute__((ext_vector_type(8)));
typedef float f32x4 __attribute__((ext_vector_type(4)));

#define MDIM 64000
#define KD 512
#define NCOLS 514
#define BM 256
#define BN 64
#define KT 16      // K steps of 32
#define NT 8       // N tiles (cols 0..511); Nyquist analytic
#define NWG 2000   // 250 M-tiles x 8 N-tiles, %8==0

// global -> LDS direct DMA, 16B per lane, LDS dest = wave-uniform base + lane*16
#define GLOAD_LDS16(g, l)                                        \
  __builtin_amdgcn_global_load_lds(                              \
      (const __attribute__((address_space(1))) void*)(g),        \
      (__attribute__((address_space(3))) void*)(l), 16, 0, 0)

// Build interleaved f16 weight matrix Wb[n][k], n in [0,512):
//   n even -> real_kernel[n/2], n odd -> imag_kernel[n/2]
__global__ void prep_w(const float* __restrict__ rk, const float* __restrict__ ik,
                       _Float16* __restrict__ wb) {
  int n = blockIdx.x;
  int k = threadIdx.x;
  int bin = n >> 1;
  const float* src = (n & 1) ? ik : rk;
  wb[(size_t)n * KD + k] = (_Float16)src[bin * KD + k];
}

// Barrier-free main loop (r14) + register-double-buffered A prefetch pinned
// by sched_barrier(0) so the compiler cannot sink loads to their use (r14's
// measured failure: VGPR=52, loads at MFMA, 16 exposed latencies/block).
// (512,4): VGPR cap 128 >= ~100 natural -> no spill (r10 lesson).
__global__ __launch_bounds__(512, 4)
void dft_gemm(const float* __restrict__ x, const _Float16* __restrict__ wb,
              float* __restrict__ out) {
  // Bp[row][k]: the block's full B panel, rows = 64 output cols, k = 512.
  // Chunk swizzle: logical 16B chunk c of row r at phys c^(r&7).
  __shared__ _Float16 Bp[BN * KD];  // 64 KB -> 2 blocks/CU

  const int tid = threadIdx.x;
  const int l  = tid & 63;
  const int w  = tid >> 6;   // 8 waves
  const int lr = l & 15;
  const int lg = l >> 4;

  // T1: XCD swizzle (NWG%8==0). The 8 N-blocks of one M-slab -> same XCD L2.
  const int wgid = (blockIdx.x & 7) * (NWG / 8) + (blockIdx.x >> 3);
  const int mt = wgid >> 3, nt = wgid & 7;
  const int m0 = mt * BM, n0 = nt * BN;

  // ---- prologue: stage B panel once; one GLOAD = one row (64x16B = 1KB) ----
#pragma unroll
  for (int s = 0; s < 8; ++s) {
    int row = w * 8 + s;                 // wave-uniform
    int cl  = l ^ (row & 7);             // logical chunk for phys chunk l
    GLOAD_LDS16(wb + (size_t)(n0 + row) * KD + cl * 8, &Bp[row * KD]);
  }
  __syncthreads();  // the ONLY barrier: panel landed (vmcnt(0) drain)

  f32x4 acc[2][4] = {};                  // [fm][fn]
  float nyq[2] = {0.0f, 0.0f};
  const bool donyq = (nt == 0);

  // A direct: lane owns rows m0 + w*32 + fm*16 + lr, k-slice lg*8..+7 per step
  const float* a0 = x + (size_t)(m0 + w * 32 + lr) * KD + lg * 8;

#define CVT(dst, L, H)                                                  \
  {                                                                     \
    (dst)[0] = (_Float16)(L)[0]; (dst)[1] = (_Float16)(L)[1];           \
    (dst)[2] = (_Float16)(L)[2]; (dst)[3] = (_Float16)(L)[3];           \
    (dst)[4] = (_Float16)(H)[0]; (dst)[5] = (_Float16)(H)[1];           \
    (dst)[6] = (_Float16)(H)[2]; (dst)[7] = (_Float16)(H)[3];           \
  }
// Nyquist: k = kt*32+lg*8+j -> sign = (-1)^j; f32-exact
#define NYQACC(fm, L, H)                                                \
  nyq[fm] += ((L)[0] - (L)[1]) + ((L)[2] - (L)[3]) +                    \
             ((H)[0] - (H)[1]) + ((H)[2] - (H)[3]);

  f32x4 rlo[2][2], rhi[2][2];  // [parity][fm], all indices compile-time
  f16x8 av[2];

  // load + convert kt = 0
#pragma unroll
  for (int fm = 0; fm < 2; ++fm) {
    rlo[0][fm] = *reinterpret_cast<const f32x4*>(a0 + (size_t)fm * 16 * KD);
    rhi[0][fm] = *reinterpret_cast<const f32x4*>(a0 + (size_t)fm * 16 * KD + 4);
  }
#pragma unroll
  for (int fm = 0; fm < 2; ++fm) {
    CVT(av[fm], rlo[0][fm], rhi[0][fm]);
    if (donyq) NYQACC(fm, rlo[0][fm], rhi[0][fm]);
  }

#pragma unroll
  for (int kt = 0; kt < KT; ++kt) {
    const int nb = (kt + 1) & 1;
    // ---- issue kt+1 raw loads (no consumer yet) ----
    if (kt + 1 < KT) {
#pragma unroll
      for (int fm = 0; fm < 2; ++fm) {
        rlo[nb][fm] = *reinterpret_cast<const f32x4*>(
            a0 + (size_t)fm * 16 * KD + (kt + 1) * 32);
        rhi[nb][fm] = *reinterpret_cast<const f32x4*>(
            a0 + (size_t)fm * 16 * KD + (kt + 1) * 32 + 4);
      }
    }
    __builtin_amdgcn_sched_barrier(0);  // loads may not sink below this
    // ---- compute kt from av (already converted) + LDS B ----
    {
      f16x8 bv[4];
#pragma unroll
      for (int fn = 0; fn < 4; ++fn) {
        int row = fn * 16 + lr;
        int pc  = (kt * 4 + lg) ^ (row & 7);
        bv[fn] = *reinterpret_cast<const f16x8*>(&Bp[row * KD + pc * 8]);
      }
#pragma unroll
      for (int fm = 0; fm < 2; ++fm)
#pragma unroll
        for (int fn = 0; fn < 4; ++fn)
          acc[fm][fn] = __builtin_amdgcn_mfma_f32_16x16x32_f16(
              av[fm], bv[fn], acc[fm][fn], 0, 0, 0);
    }
    __builtin_amdgcn_sched_barrier(0);  // cvt (and its vmcnt wait) stays below
    // ---- convert kt+1 (first consumer of the loads -> waitcnt lands here) --
    if (kt + 1 < KT) {
#pragma unroll
      for (int fm = 0; fm < 2; ++fm) {
        CVT(av[fm], rlo[nb][fm], rhi[nb][fm]);
        if (donyq) NYQACC(fm, rlo[nb][fm], rhi[nb][fm]);
      }
    }
  }

  // ---- epilogue: C/D layout col=lane&15, row=(lane>>4)*4+reg ----
#pragma unroll
  for (int fm = 0; fm < 2; ++fm) {
#pragma unroll
    for (int rr = 0; rr < 4; ++rr) {
      int row = m0 + w * 32 + fm * 16 + lg * 4 + rr;
      size_t base = (size_t)row * NCOLS;
#pragma unroll
      for (int fn = 0; fn < 4; ++fn)
        out[base + n0 + fn * 16 + lr] = acc[fm][fn][rr];
    }
  }

  // ---- Nyquist: col 512 = sum_n (-1)^n x[n]; col 513 = 0 ----
  if (donyq) {
#pragma unroll
    for (int fm = 0; fm < 2; ++fm) {
      float t = nyq[fm];
      t += __shfl_xor(t, 16);
      t += __shfl_xor(t, 32);
      if (lg == 0) {
        size_t base = (size_t)(m0 + w * 32 + fm * 16 + lr) * NCOLS;
        out[base + 512] = t;
        out[base + 513] = 0.0f;
      }
    }
  }
#undef CVT
#undef NYQACC
}

extern "C" void kernel_launch(void* const* d_in, const int* in_sizes, int n_in,
                              void* d_out, int out_size, void* d_ws, size_t ws_size,
                              hipStream_t stream) {
  const float* x  = (const float*)d_in[0];
  const float* rk = (const float*)d_in[1];
  const float* ik = (const float*)d_in[2];
  float* out = (float*)d_out;
  _Float16* wb = (_Float16*)d_ws;  // 512*512*2 B = 512 KB scratch

  prep_w<<<dim3(KD), dim3(KD), 0, stream>>>(rk, ik, wb);

  dim3 grid(NWG);
  dft_gemm<<<grid, dim3(512), 0, stream>>>(x, wb, out);
}

// Round 16
// 81.977 us; speedup vs baseline: 1.7478x; 1.7262x over previous
//
#include <hip/hip_runtime.h>

typedef _Float16 f16x8 __attribute__((ext_vector_type(8)));
typedef float f32x4 __attribute__((ext_vector_type(4)));

#define MDIM 64000
#define KDIM 512
#define NCOLS 514
#define NPAD 512
#define BM 128
#define BN 128
#define BK 64
#define KT (KDIM / BK)  // 8
#define NT 4            // N tiles (cols 0..511); Nyquist cols 512/513 analytic
#define NWG 2000        // 500 M-tiles x 4 N-tiles, divisible by 8

// global -> LDS direct DMA, 16B per lane, LDS dest = wave-uniform base + lane*16
#define GLOAD_LDS16(g, l)                                        \
  __builtin_amdgcn_global_load_lds(                              \
      (const __attribute__((address_space(1))) void*)(g),        \
      (__attribute__((address_space(3))) void*)(l), 16, 0, 0)

// Build interleaved f16 weight matrix Wb[n][k], n in [0,512):
//   n even -> real_kernel[n/2], n odd -> imag_kernel[n/2]
__global__ void prep_w(const float* __restrict__ rk, const float* __restrict__ ik,
                       _Float16* __restrict__ wb) {
  int n = blockIdx.x;
  int k = threadIdx.x;
  int bin = n >> 1;
  const float* src = (n & 1) ? ik : rk;
  wb[(size_t)n * KDIM + k] = (_Float16)src[bin * KDIM + k];
}

__global__ __launch_bounds__(256, 3)
void dft_gemm(const float* __restrict__ x, const _Float16* __restrict__ wb,
              float* __restrict__ out) {
  // Session-best structure (r9, 78.2 us): single-buffered, all-global_load_lds,
  // A kept f32 in LDS (cvt on fragment read), two full barriers per K-step,
  // 48 KB LDS -> 3 blocks/CU. Latency hiding via cross-block wave TLP (m114);
  // every explicit-pipelining variant measured slower (r3/r5/r6/r8/r13/r14/r15).
  // Chunk-swizzle: logical 16B-chunk c of row r lives at physical c^(r&7),
  // achieved by inverse-swizzling the GLOBAL source address (LDS dest linear).
  __shared__ float As[BM * BK];      // 32 KB
  __shared__ _Float16 Bs[BN * BK];   // 16 KB -> 48 KB total

  const int tid = threadIdx.x;
  const int l   = tid & 63;
  const int w   = tid >> 6;
  const int lr  = l & 15;   // fragment row/col lane index
  const int lg  = l >> 4;   // lane k-group 0..3
  const int wm  = (w >> 1) * 64;
  const int wn  = (w & 1) * 64;

  // T1: XCD swizzle (NWG%8==0 -> chunked bijection). Consecutive wgid -> same
  // XCD, so the 4 N-tile blocks of one M-tile share the x slab in one L2.
  const int wgid = (blockIdx.x & 7) * (NWG / 8) + (blockIdx.x >> 3);
  const int mt = wgid >> 2;
  const int nt = wgid & 3;
  const int m0 = mt * BM;
  const int n0 = nt * BN;

  f32x4 acc[4][4] = {};
  float nyq = 0.0f;

  // staging lane decomposition
  const int arl = l >> 4;  // A: row-within-issue 0..3
  const int acp = l & 15;  // A: phys 16B chunk 0..15 (4 floats)
  const int brl = l >> 3;  // B: row-within-issue 0..7
  const int bcp = l & 7;   // B: phys 16B chunk 0..7 (8 f16)

  for (int kt = 0; kt < KT; ++kt) {
    if (kt) __syncthreads();  // WAR: prior tile's LDS reads retired

    // ---- stage A: x f32 -> LDS via global_load_lds, source pre-swizzled ----
#pragma unroll
    for (int s = 0; s < 8; ++s) {
      int r0  = w * 32 + s * 4;            // wave-uniform
      int row = r0 + arl;
      int cl  = acp ^ (row & 7);           // logical chunk to fetch
      const float* g = x + (size_t)(m0 + row) * KDIM + kt * BK + cl * 4;
      GLOAD_LDS16(g, &As[r0 * BK]);
    }
    // ---- stage B: wb f16 -> LDS via global_load_lds, source pre-swizzled ----
#pragma unroll
    for (int s = 0; s < 4; ++s) {
      int r0  = w * 32 + s * 8;            // wave-uniform
      int row = r0 + brl;
      int cl  = bcp ^ (row & 7);
      const _Float16* g = wb + (size_t)(n0 + row) * KDIM + kt * BK + cl * 8;
      GLOAD_LDS16(g, &Bs[r0 * BK]);
    }
    __syncthreads();  // drains vmcnt(0): tile landed

    // ---- MFMA: 2 k-subtiles of 32, 4x4 fragments of 16x16 per wave ----
#pragma unroll
    for (int ks = 0; ks < 2; ++ks) {
      f16x8 av[4], bv[4];
#pragma unroll
      for (int fm = 0; fm < 4; ++fm) {
        int row = wm + fm * 16 + lr;
        int c0  = ks * 8 + lg * 2;         // logical 16B chunk (4 f32)
        int sw  = row & 7;
        f32x4 lo = *reinterpret_cast<const f32x4*>(&As[row * BK + ((c0 ^ sw) << 2)]);
        f32x4 hi = *reinterpret_cast<const f32x4*>(&As[row * BK + (((c0 + 1) ^ sw) << 2)]);
        f16x8 h;
        h[0] = (_Float16)lo[0]; h[1] = (_Float16)lo[1];
        h[2] = (_Float16)lo[2]; h[3] = (_Float16)lo[3];
        h[4] = (_Float16)hi[0]; h[5] = (_Float16)hi[1];
        h[6] = (_Float16)hi[2]; h[7] = (_Float16)hi[3];
        av[fm] = h;
      }
#pragma unroll
      for (int fn = 0; fn < 4; ++fn) {
        int row = wn + fn * 16 + lr;
        int c   = (ks * 4 + lg) ^ (row & 7);  // 16B chunk (8 f16)
        bv[fn] = *reinterpret_cast<const f16x8*>(&Bs[row * BK + (c << 3)]);
      }
#pragma unroll
      for (int fm = 0; fm < 4; ++fm)
#pragma unroll
        for (int fn = 0; fn < 4; ++fn)
          acc[fm][fn] = __builtin_amdgcn_mfma_f32_16x16x32_f16(
              av[fm], bv[fn], acc[fm][fn], 0, 0, 0);
    }

    // ---- Nyquist alternating sum from the landed f32 A tile (nt==0) ----
    // phys chunk c holds logical c^(row&7); logical chunk L starts at col
    // kt*64 + L*4 (even) -> signs +,-,+,- within each f32x4.
    if (nt == 0) {
      const int nrow = tid >> 1;
      const int half = tid & 1;
#pragma unroll
      for (int j = 0; j < 8; ++j) {
        int c = (half * 8 + j) ^ (nrow & 7);
        f32x4 v = *reinterpret_cast<const f32x4*>(&As[nrow * BK + (c << 2)]);
        nyq += (v[0] - v[1]) + (v[2] - v[3]);
      }
    }
  }

  // ---- epilogue: C/D layout col=lane&15, row=(lane>>4)*4+reg ----
#pragma unroll
  for (int fm = 0; fm < 4; ++fm) {
#pragma unroll
    for (int rr = 0; rr < 4; ++rr) {
      int row = m0 + wm + fm * 16 + lg * 4 + rr;
      size_t base = (size_t)row * NCOLS;
#pragma unroll
      for (int fn = 0; fn < 4; ++fn)
        out[base + n0 + wn + fn * 16 + lr] = acc[fm][fn][rr];
    }
  }

  // ---- Nyquist bin: col 512 = sum_n (-1)^n x[n], col 513 = 0 ----
  if (nt == 0) {
    float tot = nyq + __shfl_xor(nyq, 1);
    if ((tid & 1) == 0) {
      size_t base = (size_t)(m0 + (tid >> 1)) * NCOLS;
      out[base + 512] = tot;
      out[base + 513] = 0.0f;
    }
  }
}

extern "C" void kernel_launch(void* const* d_in, const int* in_sizes, int n_in,
                              void* d_out, int out_size, void* d_ws, size_t ws_size,
                              hipStream_t stream) {
  const float* x  = (const float*)d_in[0];
  const float* rk = (const float*)d_in[1];
  const float* ik = (const float*)d_in[2];
  float* out = (float*)d_out;
  _Float16* wb = (_Float16*)d_ws;  // 512*512*2 B = 512 KB scratch

  prep_w<<<dim3(NPAD), dim3(KDIM), 0, stream>>>(rk, ik, wb);

  dim3 grid(NWG);
  dft_gemm<<<grid, dim3(256), 0, stream>>>(x, wb, out);
}